// Round 2
// baseline (150.724 us; speedup 1.0000x reference)
//
#include <hip/hip_runtime.h>

#define N_NODES 5000
#define N_EDGES 160000
#define HID 64
#define BATCH 512
#define CSTRIDE 96   // per-node neighbor cap: deg ~ Poisson(32), P(>96) ~ e^-60, never binds

// ws layout (bytes):
//   0        cnt      5000 i32                  (zeroed by zero_kernel each launch)
//   20000    compact  5000*96 i32 = 1,920,000   direct adjacency list
//   1940000  h1       5000*64 f32 = 1,280,000
//   3220000  h_part   5000*64 f32 = 1,280,000
//   4500000  t_part   512*64 f32  =   131,072
//   4631072  Wl1T(256) Wr1T(256) Wl2T(4096) Wr2T(4096) Wc1hT(4096) f32

// ---------- dispatch 0: zero the per-node counters (capture-safe, no host API) ----------
__global__ __launch_bounds__(256) void zero_kernel(int* __restrict__ cnt) {
    int i = blockIdx.x * 256 + threadIdx.x;
    if (i < N_NODES) cnt[i] = 0;
}

// ---------- dispatch 1: edge build (global atomics) + weight transposes + task MLP ----------
// One atomicAdd per edge on 5000 counters (mean 32 hits each, device-scope by
// default) writes compact[] directly. vs the old 64-slice LDS sort this deletes the
// 15.4 MB slots array, its scattered RMW writes, the cnt[64][5000] uncoalesced reads,
// and the shuffle-scan in layer1.
__global__ __launch_bounds__(256) void build_kernel(
        const int* __restrict__ ei, const float* __restrict__ task_feat,
        const float* __restrict__ Wt1, const float* __restrict__ bt1,
        const float* __restrict__ Wt2, const float* __restrict__ bt2,
        const float* __restrict__ Wc1, const float* __restrict__ bc1,
        const float* __restrict__ Wl1, const float* __restrict__ Wr1,
        const float* __restrict__ Wl2, const float* __restrict__ Wr2,
        int* __restrict__ cnt, int* __restrict__ compact, float* __restrict__ t_part,
        float* __restrict__ Wl1T, float* __restrict__ Wr1T,
        float* __restrict__ Wl2T, float* __restrict__ Wr2T,
        float* __restrict__ Wc1hT) {
    int tid = threadIdx.x;
    int blk = blockIdx.x;
    __shared__ float s1[4][64];
    __shared__ float s2[4][64];

    if (blk < 625) {                      // 625*256 == 160000 exactly
        int e = blk * 256 + tid;
        int src = ei[e];                  // coalesced
        int dst = ei[N_EDGES + e];        // coalesced
        int q = atomicAdd(&cnt[dst], 1);  // device-scope L2 atomic, low contention
        if (q < CSTRIDE) compact[dst * CSTRIDE + q] = src;
    } else if (blk < 629) {
        int w = blk - 625;
        if (w == 0) {
            for (int idx = tid; idx < 4096; idx += 256) {
                int k = idx >> 6, h = idx & 63;
                Wl2T[idx] = Wl2[h * 64 + k];
            }
        } else if (w == 1) {
            for (int idx = tid; idx < 4096; idx += 256) {
                int k = idx >> 6, h = idx & 63;
                Wr2T[idx] = Wr2[h * 64 + k];
            }
        } else if (w == 2) {
            for (int idx = tid; idx < 4096; idx += 256) {
                int k = idx >> 6, h = idx & 63;
                Wc1hT[idx] = Wc1[h * 128 + k];
            }
        } else {
            int k = tid >> 6, h = tid & 63;
            Wl1T[tid] = Wl1[h * 4 + k];
            Wr1T[tid] = Wr1[h * 4 + k];
        }
    } else {
        // task MLP + t-half of classifier: 4 batch rows per block
        int grp = tid >> 6, h = tid & 63;
        int b = (blk - 629) * 4 + grp;
        float4 tf = ((const float4*)task_feat)[b];
        float4 w1 = ((const float4*)Wt1)[h];
        float v = bt1[h] + tf.x * w1.x + tf.y * w1.y + tf.z * w1.z + tf.w * w1.w;
        s1[grp][h] = fmaxf(v, 0.f);
        __syncthreads();
        const float4* w2r = (const float4*)(Wt2 + h * 64);
        const float4* s1v = (const float4*)s1[grp];
        float v2 = bt2[h];
#pragma unroll
        for (int q = 0; q < 16; q++) {
            float4 w = w2r[q]; float4 ss = s1v[q];
            v2 += ss.x * w.x + ss.y * w.y + ss.z * w.z + ss.w * w.w;
        }
        s2[grp][h] = v2;                  // no relu on 2nd task layer
        __syncthreads();
        const float4* wcr = (const float4*)(Wc1 + h * 128 + 64);
        const float4* s2v = (const float4*)s2[grp];
        float p = bc1[h];
#pragma unroll
        for (int q = 0; q < 16; q++) {
            float4 w = wcr[q]; float4 ss = s2v[q];
            p += ss.x * w.x + ss.y * w.y + ss.z * w.z + ss.w * w.w;
        }
        t_part[b * 64 + h] = p;
    }
}

// ---------- dispatch 2: layer 1 (4->64), wave per node, coalesced list read ----------
__global__ __launch_bounds__(256) void layer1_kernel(
        const float* __restrict__ x, const int* __restrict__ cnt,
        const int* __restrict__ compact,
        const float* __restrict__ Wl1T, const float* __restrict__ bl1,
        const float* __restrict__ Wr1T, float* __restrict__ h1) {
    int lane = threadIdx.x & 63, grp = threadIdx.x >> 6;
    int n = blockIdx.x * 4 + grp;
    int d = min(cnt[n], CSTRIDE);               // wave-uniform
    const int* row = compact + n * CSTRIDE;
    float4 xs = make_float4(0.f, 0.f, 0.f, 0.f);
    if (lane < d) {                             // coalesced 64-wide list read
        float4 xv = ((const float4*)x)[row[lane]];
        xs.x += xv.x; xs.y += xv.y; xs.z += xv.z; xs.w += xv.w;
    }
    if (lane + 64 < d) {                        // d>64 is ~1e-7/node; branch uniformly skipped
        float4 xv = ((const float4*)x)[row[lane + 64]];
        xs.x += xv.x; xs.y += xv.y; xs.z += xv.z; xs.w += xv.w;
    }
#pragma unroll
    for (int off = 1; off < 64; off <<= 1) {    // butterfly reduce float4
        xs.x += __shfl_xor(xs.x, off);
        xs.y += __shfl_xor(xs.y, off);
        xs.z += __shfl_xor(xs.z, off);
        xs.w += __shfl_xor(xs.w, off);
    }
    float inv = 1.f / fmaxf((float)d, 1.f);
    float m0 = xs.x * inv, m1 = xs.y * inv, m2 = xs.z * inv, m3 = xs.w * inv;
    float4 xn = ((const float4*)x)[n];
    float v = bl1[lane]
            + m0 * Wl1T[lane] + m1 * Wl1T[64 + lane]
            + m2 * Wl1T[128 + lane] + m3 * Wl1T[192 + lane]
            + xn.x * Wr1T[lane] + xn.y * Wr1T[64 + lane]
            + xn.z * Wr1T[128 + lane] + xn.w * Wr1T[192 + lane];
    h1[n * 64 + lane] = fmaxf(v, 0.f);
}

// ---------- dispatch 3: layer 2 (64->64) fused with h_part = h2 @ Wc1[:,:64].T ----------
__global__ __launch_bounds__(256) void layer2_kernel(
        const float* __restrict__ h1, const int* __restrict__ cnt,
        const int* __restrict__ compact,
        const float* __restrict__ Wl2T, const float* __restrict__ bl2,
        const float* __restrict__ Wr2T, const float* __restrict__ Wc1hT,
        float* __restrict__ h_part) {
    int h = threadIdx.x & 63, grp = threadIdx.x >> 6;
    int n = blockIdx.x * 4 + grp;
    int d = min(cnt[n], CSTRIDE);
    const int* bucket = compact + n * CSTRIDE;
    float a0 = 0.f, a1 = 0.f, a2 = 0.f, a3 = 0.f;
    int j = 0;
    for (; j + 4 <= d; j += 4) {
        int e0 = bucket[j], e1 = bucket[j + 1], e2 = bucket[j + 2], e3 = bucket[j + 3];
        a0 += h1[e0 * 64 + h];                  // each gather: 64 lanes read one 256B row
        a1 += h1[e1 * 64 + h];
        a2 += h1[e2 * 64 + h];
        a3 += h1[e3 * 64 + h];
    }
    for (; j < d; j++) a0 += h1[bucket[j] * 64 + h];
    float m = (a0 + a1 + a2 + a3) / fmaxf((float)d, 1.f);

    __shared__ float shm[4][64], shh[4][64], shh2[4][64];
    shm[grp][h] = m;
    shh[grp][h] = h1[n * 64 + h];
    __syncthreads();
    float v = bl2[h];
#pragma unroll
    for (int k = 0; k < 64; k++)
        v += shm[grp][k] * Wl2T[k * 64 + h] + shh[grp][k] * Wr2T[k * 64 + h];
    shh2[grp][h] = fmaxf(v, 0.f);
    __syncthreads();
    float p = 0.f;
#pragma unroll
    for (int k = 0; k < 64; k++) p += shh2[grp][k] * Wc1hT[k * 64 + h];
    h_part[n * 64 + h] = p;
}

// ---------- dispatch 4: scores[b,n] = sum_h relu(hp[n,h]+tp[b,h])*Wc2[h] + bc2 ----------
// 4 accumulators: quarters the dependent-fma chain (64 -> 16 deep per acc).
__global__ __launch_bounds__(256) void scores_kernel(
        const float* __restrict__ h_part, const float* __restrict__ t_part,
        const float* __restrict__ Wc2, const float* __restrict__ bc2,
        float* __restrict__ out) {
    int tid = threadIdx.x;
    int n = blockIdx.x * 256 + tid;
    bool valid = n < N_NODES;
    int nn = valid ? n : (N_NODES - 1);
    float hr[64];
    const float4* hp = (const float4*)(h_part + nn * 64);
#pragma unroll
    for (int i = 0; i < 16; i++) {
        float4 v = hp[i];
        hr[4 * i + 0] = v.x; hr[4 * i + 1] = v.y;
        hr[4 * i + 2] = v.z; hr[4 * i + 3] = v.w;
    }
    float b2 = bc2[0];
    int b0 = blockIdx.y * 8;
    for (int bb = 0; bb < 8; bb++) {
        const float* tp = t_part + (b0 + bb) * 64;   // wave-uniform -> scalar loads
        float acc0 = 0.f, acc1 = 0.f, acc2 = 0.f, acc3 = 0.f;
#pragma unroll
        for (int h = 0; h < 64; h += 4) {
            acc0 = fmaf(fmaxf(hr[h + 0] + tp[h + 0], 0.f), Wc2[h + 0], acc0);
            acc1 = fmaf(fmaxf(hr[h + 1] + tp[h + 1], 0.f), Wc2[h + 1], acc1);
            acc2 = fmaf(fmaxf(hr[h + 2] + tp[h + 2], 0.f), Wc2[h + 2], acc2);
            acc3 = fmaf(fmaxf(hr[h + 3] + tp[h + 3], 0.f), Wc2[h + 3], acc3);
        }
        if (valid)
            out[(b0 + bb) * N_NODES + n] = (acc0 + acc1) + (acc2 + acc3) + b2;
    }
}

// ---------- launch ----------
extern "C" void kernel_launch(void* const* d_in, const int* in_sizes, int n_in,
                              void* d_out, int out_size, void* d_ws, size_t ws_size,
                              hipStream_t stream) {
    const float* x    = (const float*)d_in[0];
    const int*   ei   = (const int*)d_in[1];
    const float* task = (const float*)d_in[2];
    const float* Wl1  = (const float*)d_in[3];
    const float* bl1  = (const float*)d_in[4];
    const float* Wr1  = (const float*)d_in[5];
    const float* Wl2  = (const float*)d_in[6];
    const float* bl2  = (const float*)d_in[7];
    const float* Wr2  = (const float*)d_in[8];
    const float* Wt1  = (const float*)d_in[9];
    const float* bt1  = (const float*)d_in[10];
    const float* Wt2  = (const float*)d_in[11];
    const float* bt2  = (const float*)d_in[12];
    const float* Wc1  = (const float*)d_in[13];
    const float* bc1  = (const float*)d_in[14];
    const float* Wc2  = (const float*)d_in[15];
    const float* bc2  = (const float*)d_in[16];
    float* out = (float*)d_out;

    char* ws = (char*)d_ws;
    int*   cnt     = (int*)(ws + 0);
    int*   compact = (int*)(ws + 20000);
    float* h1      = (float*)(ws + 1940000);
    float* h_part  = (float*)(ws + 3220000);
    float* t_part  = (float*)(ws + 4500000);
    float* Wl1T  = (float*)(ws + 4631072);
    float* Wr1T  = (float*)(ws + 4632096);
    float* Wl2T  = (float*)(ws + 4633120);
    float* Wr2T  = (float*)(ws + 4649504);
    float* Wc1hT = (float*)(ws + 4665888);

    zero_kernel<<<(N_NODES + 255) / 256, 256, 0, stream>>>(cnt);
    build_kernel<<<625 + 4 + BATCH / 4, 256, 0, stream>>>(
        ei, task, Wt1, bt1, Wt2, bt2, Wc1, bc1, Wl1, Wr1, Wl2, Wr2,
        cnt, compact, t_part, Wl1T, Wr1T, Wl2T, Wr2T, Wc1hT);
    layer1_kernel<<<N_NODES / 4, 256, 0, stream>>>(x, cnt, compact, Wl1T, bl1, Wr1T, h1);
    layer2_kernel<<<N_NODES / 4, 256, 0, stream>>>(h1, cnt, compact, Wl2T, bl2, Wr2T,
                                                   Wc1hT, h_part);
    scores_kernel<<<dim3(20, 64), 256, 0, stream>>>(h_part, t_part, Wc2, bc2, out);
}